// Round 7
// baseline (708.728 us; speedup 1.0000x reference)
//
#include <hip/hip_runtime.h>

#define N_NODES 100000
#define N_EDGES 3200000
#define F_IN    128
#define H_DIM   32
#define B_GR    256
#define NEG     0.2f

#define SCAN_TILE 1024
#define SCAN_NBLK ((N_NODES + SCAN_TILE - 1) / SCAN_TILE)   // 98

#define N_BIN    8
#define BIN_SZ   (N_NODES / N_BIN)       // 12500
#define BIN_CAP  450000                  // mean 400k, +84 sigma margin
#define NB2      ((BIN_CAP + 1023) / 1024)   // 440

#define CPAD     4                       // 16B counter padding (atomic line relief)

#define LIN_NODES 16

// ---- monotonic float<->uint encoding for atomicMax on floats ----
__device__ __forceinline__ unsigned fenc(float f) {
    unsigned u = __float_as_uint(f);
    return (u & 0x80000000u) ? ~u : (u | 0x80000000u);
}
__device__ __forceinline__ float fdec(unsigned u) {
    return (u & 0x80000000u) ? __uint_as_float(u & 0x7FFFFFFFu)
                             : __uint_as_float(~u);
}

// K1: xl = x@Wl, xr = x@Wr. 16 nodes/block, 2 nodes/thread, float4 LDS reads.
__global__ __launch_bounds__(256) void k_linear(
    const float* __restrict__ x, const float* __restrict__ Wl,
    const float* __restrict__ Wr, float* __restrict__ xl, float* __restrict__ xr)
{
    __shared__ float Wls[F_IN * H_DIM];
    __shared__ float Wrs[F_IN * H_DIM];
    __shared__ float xs[LIN_NODES * F_IN];
    int t = threadIdx.x;
    for (int i = t; i < F_IN * H_DIM; i += 256) { Wls[i] = Wl[i]; Wrs[i] = Wr[i]; }
    size_t base = (size_t)blockIdx.x * LIN_NODES;
    const float4* xg = (const float4*)(x + base * F_IN);
    float4* xs4 = (float4*)xs;
    xs4[t] = xg[t];
    xs4[t + 256] = xg[t + 256];
    __syncthreads();
    int nl = t >> 5, h = t & 31;
    float al0 = 0.f, ar0 = 0.f, al1 = 0.f, ar1 = 0.f;
    const float4* xa4 = (const float4*)(xs + nl * F_IN);
    const float4* xb4 = (const float4*)(xs + (nl + 8) * F_IN);
    #pragma unroll 8
    for (int f4 = 0; f4 < 32; ++f4) {
        float4 xa = xa4[f4], xb = xb4[f4];
        int fb = f4 * 4;
        float w;
        w = Wls[(fb + 0) * 32 + h]; al0 = fmaf(xa.x, w, al0); al1 = fmaf(xb.x, w, al1);
        w = Wls[(fb + 1) * 32 + h]; al0 = fmaf(xa.y, w, al0); al1 = fmaf(xb.y, w, al1);
        w = Wls[(fb + 2) * 32 + h]; al0 = fmaf(xa.z, w, al0); al1 = fmaf(xb.z, w, al1);
        w = Wls[(fb + 3) * 32 + h]; al0 = fmaf(xa.w, w, al0); al1 = fmaf(xb.w, w, al1);
        w = Wrs[(fb + 0) * 32 + h]; ar0 = fmaf(xa.x, w, ar0); ar1 = fmaf(xb.x, w, ar1);
        w = Wrs[(fb + 1) * 32 + h]; ar0 = fmaf(xa.y, w, ar0); ar1 = fmaf(xb.y, w, ar1);
        w = Wrs[(fb + 2) * 32 + h]; ar0 = fmaf(xa.z, w, ar0); ar1 = fmaf(xb.z, w, ar1);
        w = Wrs[(fb + 3) * 32 + h]; ar0 = fmaf(xa.w, w, ar0); ar1 = fmaf(xb.w, w, ar1);
    }
    size_t n0 = base + nl, n1 = base + nl + 8;
    xl[n0 * 32 + h] = al0; xr[n0 * 32 + h] = ar0;
    xl[n1 * 32 + h] = al1; xr[n1 * 32 + h] = ar1;
}

// K2: fused histogram (padded counters) + bin partition.
// Packed u32: (dst_local << 17) | src.
__global__ __launch_bounds__(256) void k_part(
    const int* __restrict__ ei, int* __restrict__ cnt4,
    int* __restrict__ bcnt, unsigned* __restrict__ binbuf)
{
    __shared__ int lcnt[N_BIN];
    __shared__ int lbase[N_BIN];
    int t = threadIdx.x;
    if (t < N_BIN) lcnt[t] = 0;
    __syncthreads();
    int i = blockIdx.x * 256 + t;                    // group of 4 edges
    int4 s = ((const int4*)ei)[i];
    int4 d = ((const int4*)(ei + N_EDGES))[i];
    atomicAdd(&cnt4[d.x * CPAD], 1);
    atomicAdd(&cnt4[d.y * CPAD], 1);
    atomicAdd(&cnt4[d.z * CPAD], 1);
    atomicAdd(&cnt4[d.w * CPAD], 1);
    int b0 = d.x / BIN_SZ, b1 = d.y / BIN_SZ, b2 = d.z / BIN_SZ, b3 = d.w / BIN_SZ;
    int o0 = atomicAdd(&lcnt[b0], 1);
    int o1 = atomicAdd(&lcnt[b1], 1);
    int o2 = atomicAdd(&lcnt[b2], 1);
    int o3 = atomicAdd(&lcnt[b3], 1);
    __syncthreads();
    if (t < N_BIN) lbase[t] = atomicAdd(&bcnt[t], lcnt[t]);
    __syncthreads();
    binbuf[b0 * BIN_CAP + lbase[b0] + o0] = ((unsigned)(d.x - b0 * BIN_SZ) << 17) | (unsigned)s.x;
    binbuf[b1 * BIN_CAP + lbase[b1] + o1] = ((unsigned)(d.y - b1 * BIN_SZ) << 17) | (unsigned)s.y;
    binbuf[b2 * BIN_CAP + lbase[b2] + o2] = ((unsigned)(d.z - b2 * BIN_SZ) << 17) | (unsigned)s.z;
    binbuf[b3 * BIN_CAP + lbase[b3] + o3] = ((unsigned)(d.w - b3 * BIN_SZ) << 17) | (unsigned)s.w;
}

// K3a: per-tile exclusive scan over padded counters
__global__ __launch_bounds__(256) void k_scan_a(
    const int* __restrict__ cnt4, int* __restrict__ part, int* __restrict__ bsum)
{
    __shared__ int s[256];
    int b = blockIdx.x, t = threadIdx.x;
    int base = b * SCAN_TILE + t * 4;
    int v[4], sum = 0;
    #pragma unroll
    for (int i = 0; i < 4; ++i) {
        int idx = base + i;
        v[i] = (idx < N_NODES) ? cnt4[idx * CPAD] : 0;
        sum += v[i];
    }
    s[t] = sum; __syncthreads();
    for (int off = 1; off < 256; off <<= 1) {
        int x = (t >= off) ? s[t - off] : 0;
        __syncthreads();
        s[t] += x;
        __syncthreads();
    }
    int run = (t > 0) ? s[t - 1] : 0;
    #pragma unroll
    for (int i = 0; i < 4; ++i) {
        int idx = base + i;
        if (idx < N_NODES) part[idx] = run;
        run += v[i];
    }
    if (t == 255) bsum[b] = s[255];
}

// K3b: scan the 98 block sums (exclusive, in place)
__global__ __launch_bounds__(128) void k_scan_b(int* __restrict__ bsum)
{
    __shared__ int s[128];
    int t = threadIdx.x;
    s[t] = (t < SCAN_NBLK) ? bsum[t] : 0; __syncthreads();
    for (int off = 1; off < 128; off <<= 1) {
        int x = (t >= off) ? s[t - off] : 0;
        __syncthreads();
        s[t] += x;
        __syncthreads();
    }
    if (t < SCAN_NBLK) bsum[t] = (t > 0) ? s[t - 1] : 0;
}

// K3c: combine, write rowstart + padded cursor
__global__ __launch_bounds__(256) void k_scan_c(
    const int* __restrict__ part, const int* __restrict__ bsum,
    int* __restrict__ rowstart, int* __restrict__ cursor4)
{
    int i = blockIdx.x * 256 + threadIdx.x;
    if (i < N_NODES) {
        int v = part[i] + bsum[i >> 10];
        rowstart[i] = v;
        cursor4[i * CPAD] = v;
    }
    if (i == 0) rowstart[N_NODES] = N_EDGES;
}

// K4: per-bin scatter into dst-sorted CSR. bin = blockIdx & 7 (XCD-affine).
__global__ __launch_bounds__(256) void k_scatter(
    const unsigned* __restrict__ binbuf, const int* __restrict__ bcnt,
    int* __restrict__ cursor4, int* __restrict__ srt)
{
    int bin = blockIdx.x & (N_BIN - 1);
    int blk = blockIdx.x >> 3;
    int n = bcnt[bin];
    int base = blk * 1024 + threadIdx.x * 4;
    if (base >= n) return;
    uint4 e4 = *((const uint4*)(binbuf + (size_t)bin * BIN_CAP + base));
    unsigned ev[4] = {e4.x, e4.y, e4.z, e4.w};
    int lo = bin * BIN_SZ;
    #pragma unroll
    for (int k = 0; k < 4; ++k) {
        if (base + k < n) {
            int dloc = (int)(ev[k] >> 17), src = (int)(ev[k] & 0x1FFFFu);
            int p = atomicAdd(&cursor4[(lo + dloc) * CPAD], 1);
            srt[p] = src;
        }
    }
}

// K5: fused score + softmax (no max pass) + aggregate + pool.
// Wave = node; 8 groups x 8 lanes; group = edge, lane = 4 h's (float4).
// Score dot: in-lane 4-wide fma + 3-step shfl butterfly within the group.
// Cross-group combine once per node at the end.
__global__ __launch_bounds__(256) void k_aggregate(
    const int* __restrict__ rowstart, const int* __restrict__ srt,
    const float* __restrict__ xl, const float* __restrict__ xr,
    const float* __restrict__ att, const float* __restrict__ bias,
    const int* __restrict__ batch, unsigned* __restrict__ gu)
{
    int t = threadIdx.x;
    int L = t & 63;
    int node = blockIdx.x * 4 + (t >> 6);
    int g = L >> 3, hq = L & 7;

    const float4 xr4  = ((const float4*)(xr + (size_t)node * H_DIM))[hq];
    const float4 att4 = ((const float4*)att)[hq];

    int e0 = rowstart[node], e1 = rowstart[node + 1];
    int nit = e1 - e0 + 1;              // + virtual self-loop at j == e1

    float z = 0.f;
    float ax = 0.f, ay = 0.f, az = 0.f, aw = 0.f;

    for (int it = 0; it < nit; it += 8) {
        int idx = it + g;
        int j = e0 + idx;
        int s = srt[min(j, N_EDGES - 1)];
        if (j >= e1) s = node;          // self-loop or invalid lane (p forced 0)
        float4 xs = ((const float4*)(xl + (size_t)s * H_DIM))[hq];
        float vx = xs.x + xr4.x; vx = fmaxf(vx, vx * NEG);
        float vy = xs.y + xr4.y; vy = fmaxf(vy, vy * NEG);
        float vz = xs.z + xr4.z; vz = fmaxf(vz, vz * NEG);
        float vw = xs.w + xr4.w; vw = fmaxf(vw, vw * NEG);
        float pr = vx * att4.x;
        pr = fmaf(vy, att4.y, pr);
        pr = fmaf(vz, att4.z, pr);
        pr = fmaf(vw, att4.w, pr);
        pr += __shfl_xor(pr, 1);
        pr += __shfl_xor(pr, 2);
        pr += __shfl_xor(pr, 4);
        float p = __expf(fminf(pr, 70.f));
        if (idx >= nit) p = 0.f;
        z += p;
        ax = fmaf(p, xs.x, ax);
        ay = fmaf(p, xs.y, ay);
        az = fmaf(p, xs.z, az);
        aw = fmaf(p, xs.w, aw);
    }

    // combine the 8 groups (butterfly over strides 8,16,32)
    #pragma unroll
    for (int st = 8; st <= 32; st <<= 1) {
        z  += __shfl_xor(z,  st);
        ax += __shfl_xor(ax, st);
        ay += __shfl_xor(ay, st);
        az += __shfl_xor(az, st);
        aw += __shfl_xor(aw, st);
    }

    if (L < 8) {
        const float4 b4 = ((const float4*)bias)[hq];
        int gb = batch[node] * H_DIM + hq * 4;
        atomicMax(&gu[gb + 0], fenc(ax / z + b4.x));
        atomicMax(&gu[gb + 1], fenc(ay / z + b4.y));
        atomicMax(&gu[gb + 2], fenc(az / z + b4.z));
        atomicMax(&gu[gb + 3], fenc(aw / z + b4.w));
    }
}

// K6: h1 = relu(g @ W1 + b1)
__global__ __launch_bounds__(256) void k_mlp1(
    const unsigned* __restrict__ gu, const float* __restrict__ W1,
    const float* __restrict__ b1, float* __restrict__ h1)
{
    __shared__ float gs[H_DIM];
    int b = blockIdx.x, t = threadIdx.x;
    if (t < H_DIM) gs[t] = fdec(gu[b * H_DIM + t]);
    __syncthreads();
    for (int jj = 0; jj < 4; ++jj) {
        int j = jj * 256 + t;
        float a = b1[j];
        #pragma unroll
        for (int k = 0; k < H_DIM; ++k) a = fmaf(gs[k], W1[k * 1024 + j], a);
        h1[(size_t)b * 1024 + j] = fmaxf(a, 0.f);
    }
}

// K7: h2 = relu(h1 @ W2 + b2), 4 graphs per block
__global__ __launch_bounds__(512) void k_mlp2(
    const float* __restrict__ h1, const float* __restrict__ W2,
    const float* __restrict__ b2, float* __restrict__ h2)
{
    __shared__ float hs[4][1024];
    int b0 = blockIdx.x * 4, t = threadIdx.x;
    for (int r = 0; r < 4; ++r)
        for (int k = t; k < 1024; k += 512) hs[r][k] = h1[(size_t)(b0 + r) * 1024 + k];
    __syncthreads();
    float bb = b2[t];
    float a0 = bb, a1 = bb, a2 = bb, a3 = bb;
    for (int k = 0; k < 1024; ++k) {
        float w = W2[(size_t)k * 512 + t];
        a0 = fmaf(hs[0][k], w, a0);
        a1 = fmaf(hs[1][k], w, a1);
        a2 = fmaf(hs[2][k], w, a2);
        a3 = fmaf(hs[3][k], w, a3);
    }
    h2[(size_t)(b0 + 0) * 512 + t] = fmaxf(a0, 0.f);
    h2[(size_t)(b0 + 1) * 512 + t] = fmaxf(a1, 0.f);
    h2[(size_t)(b0 + 2) * 512 + t] = fmaxf(a2, 0.f);
    h2[(size_t)(b0 + 3) * 512 + t] = fmaxf(a3, 0.f);
}

// K8: out = h2 @ W3 + b3
__global__ __launch_bounds__(256) void k_mlp3(
    const float* __restrict__ h2, const float* __restrict__ W3,
    const float* __restrict__ b3, float* __restrict__ out)
{
    int b = blockIdx.x, t = threadIdx.x;
    int c = t >> 6, lane = t & 63;
    float a = 0.f;
    for (int k = lane; k < 512; k += 64)
        a = fmaf(h2[(size_t)b * 512 + k], W3[k * 4 + c], a);
    for (int off = 32; off; off >>= 1) a += __shfl_down(a, off);
    if (lane == 0) out[b * 4 + c] = a + b3[c];
}

extern "C" void kernel_launch(void* const* d_in, const int* in_sizes, int n_in,
                              void* d_out, int out_size, void* d_ws, size_t ws_size,
                              hipStream_t stream)
{
    const float* x     = (const float*)d_in[0];
    const int*   ei    = (const int*)d_in[1];
    const int*   batch = (const int*)d_in[2];
    const float* Wl    = (const float*)d_in[3];
    const float* Wr    = (const float*)d_in[4];
    const float* att   = (const float*)d_in[5];
    const float* bias  = (const float*)d_in[6];
    const float* W1    = (const float*)d_in[7];
    const float* b1    = (const float*)d_in[8];
    const float* W2    = (const float*)d_in[9];
    const float* b2    = (const float*)d_in[10];
    const float* W3    = (const float*)d_in[11];
    const float* b3    = (const float*)d_in[12];
    float* out = (float*)d_out;

    // workspace layout (xl aliases binbuf: binbuf dead before k_linear runs)
    int*      srt      = (int*)d_ws;                         // 3.2M
    int*      rowstart = srt + N_EDGES;                      // 100001
    int*      part     = rowstart + N_NODES + 1;             // 100000
    int*      bsum     = part + N_NODES;                     // 128
    int*      cnt4     = bsum + 128;                         // 400000 [memset]
    int*      bcnt     = cnt4 + N_NODES * CPAD;              // 8      [memset]
    unsigned* gu       = (unsigned*)(bcnt + 8);              // 8192   [memset]
    int*      cursor4  = (int*)(gu + B_GR * H_DIM);          // 400000
    float*    h1       = (float*)(cursor4 + N_NODES * CPAD); // 262144
    float*    h2       = h1 + (size_t)B_GR * 1024;           // 131072
    unsigned* binbuf   = (unsigned*)(h2 + (size_t)B_GR * 512); // 3.6M
    float*    xl       = (float*)binbuf;                     // 3.2M (alias)
    float*    xr       = (float*)(binbuf + (size_t)N_BIN * BIN_CAP); // 3.2M

    hipMemsetAsync(cnt4, 0,
                   (size_t)(N_NODES * CPAD + 8 + B_GR * H_DIM) * sizeof(int), stream);

    k_part  <<<N_EDGES / 4 / 256, 256, 0, stream>>>(ei, cnt4, bcnt, binbuf);
    k_scan_a<<<SCAN_NBLK, 256, 0, stream>>>(cnt4, part, bsum);
    k_scan_b<<<1, 128, 0, stream>>>(bsum);
    k_scan_c<<<(N_NODES + 255) / 256, 256, 0, stream>>>(part, bsum, rowstart, cursor4);
    k_scatter<<<NB2 * N_BIN, 256, 0, stream>>>(binbuf, bcnt, cursor4, srt);
    k_linear<<<N_NODES / LIN_NODES, 256, 0, stream>>>(x, Wl, Wr, xl, xr);
    k_aggregate<<<N_NODES / 4, 256, 0, stream>>>(
        rowstart, srt, xl, xr, att, bias, batch, gu);
    k_mlp1<<<B_GR, 256, 0, stream>>>(gu, W1, b1, h1);
    k_mlp2<<<B_GR / 4, 512, 0, stream>>>(h1, W2, b2, h2);
    k_mlp3<<<B_GR, 256, 0, stream>>>(h2, W3, b3, out);
}